// Round 16
// baseline (140.948 us; speedup 1.0000x reference)
//
#include <hip/hip_runtime.h>
#include <hip/hip_bf16.h>

// MultiLatentAttention on MI355X.
// causal mask t<=l with L=64 => attention only over first 64 tokens.
// out[b] = softmax_groups(x@Wg) @ M[b],  M built from attn_out and Wp (MFMA).
// Round 16: revert r15's kv-fold (regressed) to the r14 structure; A/B test
// 32x32x16 MFMA shape in the gates GEMM (half the MFMA instructions, same
// staging/swizzle) vs the 16x16x32 out-projection control.

typedef __attribute__((ext_vector_type(8))) short bf16x8;
typedef __attribute__((ext_vector_type(4))) float f32x4;
typedef __attribute__((ext_vector_type(16))) float f32x16;
typedef __attribute__((ext_vector_type(4))) unsigned short us4;

__device__ __forceinline__ void gll16(const void* g, void* l) {
  __builtin_amdgcn_global_load_lds((const __attribute__((address_space(1))) void*)g,
                                   (__attribute__((address_space(3))) void*)l, 16, 0, 0);
}

// ---------------- prep: x->bf16 (blocks 0..2047) + 4 weight transposes (2048..6143) ----------
__global__ __launch_bounds__(256)
void prep_kernel(const float* __restrict__ x, __hip_bfloat16* __restrict__ xb,
                 const float* __restrict__ Wg, const float* __restrict__ Wk,
                 const float* __restrict__ Wv, const float* __restrict__ Wp,
                 __hip_bfloat16* __restrict__ WgT, __hip_bfloat16* __restrict__ WkT,
                 __hip_bfloat16* __restrict__ WvT, __hip_bfloat16* __restrict__ WpT) {
  const int bid = blockIdx.x, tid = threadIdx.x;
  if (bid < 2048) {
    const int stride = 2048 * 256;
    for (int i = bid * 256 + tid; i < 4194304; i += stride) {
      float4 f = reinterpret_cast<const float4*>(x)[i];
      union { __hip_bfloat16 h[4]; us4 v; } u;
      u.h[0] = __float2bfloat16(f.x);
      u.h[1] = __float2bfloat16(f.y);
      u.h[2] = __float2bfloat16(f.z);
      u.h[3] = __float2bfloat16(f.w);
      reinterpret_cast<us4*>(xb)[i] = u.v;
    }
  } else {
    const int t = bid - 2048;
    const int z = t >> 10, rem = t & 1023;
    const float* W = (z == 0) ? Wg : ((z == 1) ? Wk : ((z == 2) ? Wv : Wp));
    __hip_bfloat16* Wt = (z == 0) ? WgT : ((z == 1) ? WkT : ((z == 2) ? WvT : WpT));
    __shared__ float tile[32][33];
    const int bx = (rem & 31) * 32, by = (rem >> 5) * 32;
    const int tx = tid & 31, ty = tid >> 5;  // 32x8
    #pragma unroll
    for (int j = 0; j < 32; j += 8)
      tile[ty + j][tx] = W[(size_t)(by + ty + j) * 1024 + bx + tx];
    __syncthreads();
    #pragma unroll
    for (int j = 0; j < 32; j += 8)
      Wt[(size_t)(bx + ty + j) * 1024 + by + tx] = __float2bfloat16(tile[tx][ty + j]);
  }
}

// ---------------- gates GEMM: 256x256 2-phase, 32x32x16 MFMA (A-arm) ----------------
// Same staging/swizzle as the proven 16x16 kernel; fragments remapped for 32x32x16:
// A row=lane&31, k=(lane>>5)*8+e; B col=lane&31 same k; C row=(reg&3)+8*(reg>>2)+4*(lane>>5),
// col=lane&31 (guide-verified m74/m101). Per K-tile: 24 ds_read (same), 32 MFMA (half).
// Epilogue: per-64-column-group softmax (row's 64 vals in 32 same-hi lanes x 2 n-frags).
__global__ __launch_bounds__(512, 2)
void gemm_g32(const __hip_bfloat16* __restrict__ A, const __hip_bfloat16* __restrict__ Bt,
              __hip_bfloat16* __restrict__ G) {
  __shared__ __align__(16) unsigned short SA[2][256 * 64];
  __shared__ __align__(16) unsigned short SB[2][256 * 64];
  const int tid = threadIdx.x;
  const int lane = tid & 63;
  const int w = tid >> 6;            // wave 0..7
  const int wm = w >> 2, wn = w & 3; // 2x4 wave grid; per-wave out = 128x64
  const int l5 = lane & 31, hi = lane >> 5;
  const int m0 = blockIdx.x * 256, n0 = blockIdx.y * 256;
  const int K = 1024;

  f32x16 acc[4][2] = {};

  auto STAGE = [&](int bsel, int kt) {
    #pragma unroll
    for (int r = 0; r < 4; ++r) {
      int c = r * 512 + tid;          // chunk 0..2047: row=c>>3, slot=c&7
      int row = c >> 3, slot = c & 7;
      int gch = slot ^ (row & 7);     // pre-swizzled global chunk
      gll16(A + (size_t)(m0 + row) * K + kt + gch * 8, (char*)&SA[bsel][0] + c * 16);
      gll16(Bt + (size_t)(n0 + row) * K + kt + gch * 8, (char*)&SB[bsel][0] + c * 16);
    }
  };

  STAGE(0, 0);
  __syncthreads();

  int buf = 0;
  for (int t = 0; t < 16; ++t) {
    if (t + 1 < 16) STAGE(buf ^ 1, (t + 1) << 6);

    #pragma unroll
    for (int kk = 0; kk < 4; ++kk) {
      const int kc = kk * 2 + hi;     // logical 8-elem k-chunk
      bf16x8 b0, b1, a[4];
      {
        int row = wn * 64 + l5;
        b0 = *(const bf16x8*)&SB[buf][row * 64 + (kc ^ (row & 7)) * 8];
        row = wn * 64 + 32 + l5;
        b1 = *(const bf16x8*)&SB[buf][row * 64 + (kc ^ (row & 7)) * 8];
      }
      #pragma unroll
      for (int mi = 0; mi < 4; ++mi) {
        int row = wm * 128 + mi * 32 + l5;
        a[mi] = *(const bf16x8*)&SA[buf][row * 64 + (kc ^ (row & 7)) * 8];
      }
      #pragma unroll
      for (int mi = 0; mi < 4; ++mi) {
        acc[mi][0] = __builtin_amdgcn_mfma_f32_32x32x16_bf16(a[mi], b0, acc[mi][0], 0, 0, 0);
        acc[mi][1] = __builtin_amdgcn_mfma_f32_32x32x16_bf16(a[mi], b1, acc[mi][1], 0, 0, 0);
      }
    }
    __syncthreads();
    buf ^= 1;
  }

  // Epilogue softmax: wave's 64 columns = one group (head h). Row r's 64 values are in
  // the 32 lanes sharing hi (cols l5 and 32+l5).
  #pragma unroll
  for (int mi = 0; mi < 4; ++mi) {
    #pragma unroll
    for (int r = 0; r < 16; ++r) {
      float v0 = acc[mi][0][r], v1 = acc[mi][1][r];
      float mx = fmaxf(v0, v1);
      mx = fmaxf(mx, __shfl_xor(mx, 1));
      mx = fmaxf(mx, __shfl_xor(mx, 2));
      mx = fmaxf(mx, __shfl_xor(mx, 4));
      mx = fmaxf(mx, __shfl_xor(mx, 8));
      mx = fmaxf(mx, __shfl_xor(mx, 16));
      float e0 = __expf(v0 - mx), e1 = __expf(v1 - mx);
      float s = e0 + e1;
      s += __shfl_xor(s, 1);
      s += __shfl_xor(s, 2);
      s += __shfl_xor(s, 4);
      s += __shfl_xor(s, 8);
      s += __shfl_xor(s, 16);
      float inv = 1.0f / s;
      int row = m0 + wm * 128 + mi * 32 + (r & 3) + 8 * (r >> 2) + 4 * hi;
      G[(size_t)row * 1024 + n0 + wn * 64 + l5]      = __float2bfloat16(e0 * inv);
      G[(size_t)row * 1024 + n0 + wn * 64 + 32 + l5] = __float2bfloat16(e1 * inv);
    }
  }
}

// ---------------- 256x256 2-phase pipelined bf16 GEMM (proven ~48.7us) — out projection -----
__global__ __launch_bounds__(512, 2)
void gemm256o(const __hip_bfloat16* __restrict__ A, const __hip_bfloat16* __restrict__ Bt,
              float* __restrict__ Cv, int K, int ldc,
              long long astride, long long bstride, long long cstride) {
  __shared__ __align__(16) unsigned short SA[2][256 * 64];
  __shared__ __align__(16) unsigned short SB[2][256 * 64];
  const int tid = threadIdx.x;
  const int lane = tid & 63;
  const int w = tid >> 6;
  const int wm = w >> 2, wn = w & 3;
  const int lr = lane & 15, lk = lane >> 4;
  const int m0 = blockIdx.x * 256, n0 = blockIdx.y * 256;
  const long long b = blockIdx.z;
  const __hip_bfloat16* Ab = A + b * astride;
  const __hip_bfloat16* Bb = Bt + b * bstride;

  f32x4 acc[8][4] = {};

  const int NT = K >> 6;
  int buf = 0;

  auto STAGE = [&](int bsel, int kt) {
    #pragma unroll
    for (int r = 0; r < 4; ++r) {
      int c = r * 512 + tid;
      int row = c >> 3, slot = c & 7;
      int gch = slot ^ (row & 7);
      gll16(Ab + (size_t)(m0 + row) * K + kt + gch * 8, (char*)&SA[bsel][0] + c * 16);
      gll16(Bb + (size_t)(n0 + row) * K + kt + gch * 8, (char*)&SB[bsel][0] + c * 16);
    }
  };

  STAGE(0, 0);
  __syncthreads();

  for (int t = 0; t < NT; ++t) {
    if (t + 1 < NT) STAGE(buf ^ 1, (t + 1) << 6);

    bf16x8 bfr[2][4];
    #pragma unroll
    for (int kk = 0; kk < 2; ++kk)
      #pragma unroll
      for (int ni = 0; ni < 4; ++ni) {
        int row = wn * 64 + ni * 16 + lr;
        int ch = (kk * 4 + lk) ^ (row & 7);
        bfr[kk][ni] = *(const bf16x8*)&SB[buf][row * 64 + ch * 8];
      }
    #pragma unroll
    for (int mi = 0; mi < 8; ++mi) {
      int row = wm * 128 + mi * 16 + lr;
      int ch0 = lk ^ (row & 7);
      int ch1 = (4 + lk) ^ (row & 7);
      bf16x8 a0 = *(const bf16x8*)&SA[buf][row * 64 + ch0 * 8];
      bf16x8 a1 = *(const bf16x8*)&SA[buf][row * 64 + ch1 * 8];
      #pragma unroll
      for (int ni = 0; ni < 4; ++ni)
        acc[mi][ni] = __builtin_amdgcn_mfma_f32_16x16x32_bf16(a0, bfr[0][ni], acc[mi][ni], 0, 0, 0);
      #pragma unroll
      for (int ni = 0; ni < 4; ++ni)
        acc[mi][ni] = __builtin_amdgcn_mfma_f32_16x16x32_bf16(a1, bfr[1][ni], acc[mi][ni], 0, 0, 0);
    }
    __syncthreads();
    buf ^= 1;
  }

  float* C = Cv + b * cstride;
  #pragma unroll
  for (int mi = 0; mi < 8; ++mi) {
    int r = m0 + wm * 128 + mi * 16 + lk * 4;
    #pragma unroll
    for (int ni = 0; ni < 4; ++ni) {
      int c = n0 + wn * 64 + ni * 16 + lr;
      #pragma unroll
      for (int jj = 0; jj < 4; ++jj)
        C[(size_t)(r + jj) * ldc + c] = acc[mi][ni][jj];
    }
  }
}

// ---------------- kv projection, split-K=8: kvp[ks][256][2048] fp32 partials ----------------
// Stacked rows (b*64+t, t<64). 128x128 tile, BK=32, 4 waves, 4 K-iters/block, grid (2,16,8).
__global__ __launch_bounds__(256)
void gemm_kv(const __hip_bfloat16* __restrict__ A, const __hip_bfloat16* __restrict__ Bt,
             float* __restrict__ kvp) {
  __shared__ __align__(16) unsigned short As[128 * 32];
  __shared__ __align__(16) unsigned short Bs[128 * 32];
  const int tid = threadIdx.x;
  const int lane = tid & 63;
  const int w = tid >> 6;
  const int wm = w >> 1, wn = w & 1;
  const int lr = lane & 15, lk = lane >> 4;
  const int m0 = blockIdx.x * 128, n0 = blockIdx.y * 128;
  const int ks = blockIdx.z;
  const int K = 1024;

  f32x4 acc[4][4] = {};
  const int r0 = tid >> 2;
  const int c8 = (tid & 3) * 8;

  auto xrow = [&](int rg) { return (size_t)(rg >> 6) * 4096 + (rg & 63); };

  for (int ki = 0; ki < 4; ++ki) {
    int kt = ks * 128 + ki * 32;
    __syncthreads();
    gll16(A + xrow(m0 + r0) * K + kt + c8,      (char*)As + (w * 64) * 16);
    gll16(Bt + (size_t)(n0 + r0) * K + kt + c8, (char*)Bs + (w * 64) * 16);
    gll16(A + xrow(m0 + 64 + r0) * K + kt + c8,      (char*)As + (256 + w * 64) * 16);
    gll16(Bt + (size_t)(n0 + 64 + r0) * K + kt + c8, (char*)Bs + (256 + w * 64) * 16);
    __syncthreads();

    bf16x8 af[4], bf[4];
    #pragma unroll
    for (int mi = 0; mi < 4; ++mi)
      af[mi] = *(const bf16x8*)&As[(wm * 64 + mi * 16 + lr) * 32 + lk * 8];
    #pragma unroll
    for (int ni = 0; ni < 4; ++ni)
      bf[ni] = *(const bf16x8*)&Bs[(wn * 64 + ni * 16 + lr) * 32 + lk * 8];
    #pragma unroll
    for (int mi = 0; mi < 4; ++mi)
      #pragma unroll
      for (int ni = 0; ni < 4; ++ni)
        acc[mi][ni] = __builtin_amdgcn_mfma_f32_16x16x32_bf16(af[mi], bf[ni], acc[mi][ni], 0, 0, 0);
  }

  float* C = kvp + (size_t)ks * 256 * 2048;
  #pragma unroll
  for (int mi = 0; mi < 4; ++mi) {
    int r = m0 + wm * 64 + mi * 16 + lk * 4;
    #pragma unroll
    for (int ni = 0; ni < 4; ++ni) {
      int c = n0 + wn * 64 + ni * 16 + lr;
      #pragma unroll
      for (int jj = 0; jj < 4; ++jj)
        C[(size_t)(r + jj) * 2048 + c] = acc[mi][ni][jj];
    }
  }
}

// ---------------- attn (split-K sum + RoPE) + MFMA Mt build, merged: grid (4ct,16h,4b) -------
// WpT slice staged via gll16 FIRST (lands under attention compute). ao written to LDS bf16
// with ^(row&7) swizzle (plain ds_write). Mt_slice[256c][64l] = SW @ SAo^T via MFMA.
__global__ __launch_bounds__(256)
void attn_mt(const float* __restrict__ kvp, const float* __restrict__ lq,
             const __hip_bfloat16* __restrict__ WpT, __hip_bfloat16* __restrict__ Mt) {
  const int ct = blockIdx.x, h = blockIdx.y, b = blockIdx.z;
  __shared__ float Ks[64][64];
  __shared__ float Vs[64][64];
  __shared__ float S[64][65];   // S[l][t]
  __shared__ float Pt[64][65];  // Pt[t][l]
  __shared__ __align__(16) unsigned short SW[256 * 64];   // WpT slice [256c][64d], swizzled
  __shared__ __align__(16) unsigned short SAo[64 * 64];   // ao bf16 [64l][64d], swizzled
  const int tid = threadIdx.x;
  const int lane = tid & 63;
  const int w = tid >> 6;
  const int lr = lane & 15, lk = lane >> 4;

  // stage WpT slice early — overlaps the whole attention phase
  #pragma unroll
  for (int j = 0; j < 8; ++j) {
    int c2 = j * 256 + tid;
    int row = c2 >> 3, slot = c2 & 7;
    int gch = slot ^ (row & 7);
    gll16(WpT + (size_t)(ct * 256 + row) * 1024 + h * 64 + gch * 8, (char*)SW + c2 * 16);
  }

  // ---- K/V: sum 8 split-K partials + RoPE on K ----
  {
    int r = tid >> 4;            // 0..15
    int c4 = (tid & 15) * 4;     // head-dim col (pairs i0=c4/2, i0+1)
    int i0 = c4 >> 1;
    float inv0 = exp2f(-13.287712379549449f * ((float)i0 * (1.0f / 32.0f)));
    float inv1 = exp2f(-13.287712379549449f * ((float)(i0 + 1) * (1.0f / 32.0f)));
    #pragma unroll
    for (int j = 0; j < 4; ++j) {
      int row = j * 16 + r;      // t
      float4 kf = make_float4(0.f, 0.f, 0.f, 0.f);
      float4 vf = make_float4(0.f, 0.f, 0.f, 0.f);
      #pragma unroll
      for (int ks = 0; ks < 8; ++ks) {
        const float* base = kvp + ((size_t)ks * 256 + b * 64 + row) * 2048 + h * 64;
        float4 kp = *(const float4*)(base + c4);
        float4 vp = *(const float4*)(base + 1024 + c4);
        kf.x += kp.x; kf.y += kp.y; kf.z += kp.z; kf.w += kp.w;
        vf.x += vp.x; vf.y += vp.y; vf.z += vp.z; vf.w += vp.w;
      }
      float a0 = (float)row * inv0, a1 = (float)row * inv1;
      float s0 = sinf(a0), c0 = cosf(a0), s1 = sinf(a1), c1 = cosf(a1);
      *(float4*)&Ks[row][c4] = make_float4(kf.x * c0 - kf.y * s0, kf.x * s0 + kf.y * c0,
                                           kf.z * c1 - kf.w * s1, kf.z * s1 + kf.w * c1);
      *(float4*)&Vs[row][c4] = vf;
    }
  }
  __syncthreads();

  // ---- scores: thread = (l = lane, t-chunk = wave) ----
  {
    const int l = tid & 63;
    float q[64];
    const float4* lq4 = (const float4*)(lq + ((size_t)l * 16 + h) * 64);
    #pragma unroll
    for (int i = 0; i < 16; ++i) {
      float4 f = lq4[i];
      q[4 * i] = f.x; q[4 * i + 1] = f.y; q[4 * i + 2] = f.z; q[4 * i + 3] = f.w;
    }
    #pragma unroll
    for (int tl = 0; tl < 16; ++tl) {
      int t = w * 16 + tl;
      float a = 0.f;
      #pragma unroll
      for (int d4 = 0; d4 < 16; ++d4) {
        float4 kf = *(const float4*)&Ks[t][d4 * 4];
        a += q[4 * d4] * kf.x + q[4 * d4 + 1] * kf.y + q[4 * d4 + 2] * kf.z + q[4 * d4 + 3] * kf.w;
      }
      S[l][t] = a * 0.125f;
    }
  }
  __syncthreads();

  // ---- softmax: thread = (l = tid>>2, c = tid&3), causal t<=l ----
  {
    const int l = tid >> 2, c = tid & 3;
    float sv[16];
    float mx = -3.0e38f;
    #pragma unroll
    for (int i = 0; i < 16; ++i) {
      int t = c * 16 + i;
      sv[i] = S[l][t];
      if (t <= l) mx = fmaxf(mx, sv[i]);
    }
    mx = fmaxf(mx, __shfl_xor(mx, 1));
    mx = fmaxf(mx, __shfl_xor(mx, 2));
    float sum = 0.f;
    float e[16];
    #pragma unroll
    for (int i = 0; i < 16; ++i) {
      int t = c * 16 + i;
      e[i] = (t <= l) ? __expf(sv[i] - mx) : 0.f;
      sum += e[i];
    }
    sum += __shfl_xor(sum, 1);
    sum += __shfl_xor(sum, 2);
    float inv = 1.0f / sum;
    #pragma unroll
    for (int i = 0; i < 16; ++i) Pt[c * 16 + i][l] = e[i] * inv;
  }
  __syncthreads();

  // ---- PV: thread = (l = lane, d-chunk = wave); ao -> SAo bf16 swizzled ----
  {
    const int l = tid & 63;
    float o[16];
    #pragma unroll
    for (int i = 0; i < 16; ++i) o[i] = 0.f;
    for (int t = 0; t < 64; ++t) {
      float p = Pt[t][l];
      #pragma unroll
      for (int d4 = 0; d4 < 4; ++d4) {
        float4 vf = *(const float4*)&Vs[t][w * 16 + d4 * 4];
        o[4 * d4]     += p * vf.x;
        o[4 * d4 + 1] += p * vf.y;
        o[4 * d4 + 2] += p * vf.z;
        o[4 * d4 + 3] += p * vf.w;
      }
    }
    union { __hip_bfloat16 hh[8]; bf16x8 v; } p0, p1;
    #pragma unroll
    for (int i = 0; i < 8; ++i) { p0.hh[i] = __float2bfloat16(o[i]); p1.hh[i] = __float2bfloat16(o[8 + i]); }
    *(bf16x8*)&SAo[l * 64 + ((2 * w) ^ (l & 7)) * 8]     = p0.v;
    *(bf16x8*)&SAo[l * 64 + ((2 * w + 1) ^ (l & 7)) * 8] = p1.v;
  }
  __syncthreads();  // drains SAo ds_writes AND SW gll16 (vmcnt)

  // ---- MFMA: Mt_slice = SW @ SAo^T ----
  f32x4 acc[4][4] = {};
  bf16x8 bfr[2][4];
  #pragma unroll
  for (int kk = 0; kk < 2; ++kk)
    #pragma unroll
    for (int ni = 0; ni < 4; ++ni) {
      int row = ni * 16 + lr;
      int ch = (kk * 4 + lk) ^ (row & 7);
      bfr[kk][ni] = *(const bf16x8*)&SAo[row * 64 + ch * 8];
    }
  #pragma unroll
  for (int mi = 0; mi < 4; ++mi) {
    int row = w * 64 + mi * 16 + lr;
    int ch0 = lk ^ (row & 7);
    int ch1 = (4 + lk) ^ (row & 7);
    bf16x8 a0 = *(const bf16x8*)&SW[row * 64 + ch0 * 8];
    bf16x8 a1 = *(const bf16x8*)&SW[row * 64 + ch1 * 8];
    #pragma unroll
    for (int ni = 0; ni < 4; ++ni)
      acc[mi][ni] = __builtin_amdgcn_mfma_f32_16x16x32_bf16(a0, bfr[0][ni], acc[mi][ni], 0, 0, 0);
    #pragma unroll
    for (int ni = 0; ni < 4; ++ni)
      acc[mi][ni] = __builtin_amdgcn_mfma_f32_16x16x32_bf16(a1, bfr[1][ni], acc[mi][ni], 0, 0, 0);
  }

  // C-layout: row(c) = ct*256 + w*64 + mi*16 + lk*4 + jj, col(l) = ni*16 + lr
  #pragma unroll
  for (int mi = 0; mi < 4; ++mi) {
    int c = ct * 256 + w * 64 + mi * 16 + lk * 4;
    #pragma unroll
    for (int ni = 0; ni < 4; ++ni) {
      int l = ni * 16 + lr;
      #pragma unroll
      for (int jj = 0; jj < 4; ++jj)
        Mt[((size_t)b * 1024 + c + jj) * 1024 + h * 64 + l] = __float2bfloat16(acc[mi][ni][jj]);
    }
  }
}

extern "C" void kernel_launch(void* const* d_in, const int* in_sizes, int n_in,
                              void* d_out, int out_size, void* d_ws, size_t ws_size,
                              hipStream_t stream) {
  const float* x  = (const float*)d_in[0];
  const float* lq = (const float*)d_in[1];
  const float* Wk = (const float*)d_in[2];
  const float* Wv = (const float*)d_in[3];
  const float* Wg = (const float*)d_in[4];
  const float* Wp = (const float*)d_in[5];
  float* out = (float*)d_out;

  // workspace layout (bytes)
  char* w = (char*)d_ws;
  __hip_bfloat16* xb   = (__hip_bfloat16*)(w);              // 33,554,432
  __hip_bfloat16* G    = (__hip_bfloat16*)(w + 33554432);   // 33,554,432
  __hip_bfloat16* WgT  = (__hip_bfloat16*)(w + 67108864);   // 2,097,152
  __hip_bfloat16* WkvT = (__hip_bfloat16*)(w + 69206016);   // 4,194,304
  __hip_bfloat16* WpT  = (__hip_bfloat16*)(w + 73400320);   // 2,097,152
  __hip_bfloat16* Mt   = (__hip_bfloat16*)(w + 75497472);   // 8,388,608
  // total 83,886,080 B
  // kv partials live in d_out (16MB of its 64MB), consumed by attn_mt before
  // the final GEMM overwrites all of d_out. Deterministic.
  float* kvp = out;

  // x->bf16 + 4 weight transposes, one launch
  prep_kernel<<<6144, 256, 0, stream>>>(x, xb, Wg, Wk, Wv, Wp,
                                        WgT, WkvT, WkvT + 1024 * 1024, WpT);

  // gates: G = softmax_groups(x @ Wg), bf16 [16384,1024] — 32x32x16 MFMA (A-arm)
  gemm_g32<<<dim3(64, 4), 512, 0, stream>>>(xb, WgT, G);

  // k,v split-K partials: kvp[8][256][2048] fp32 (stacked rows b*64+t)
  gemm_kv<<<dim3(2, 16, 8), 256, 0, stream>>>(xb, WkvT, kvp);

  // attention (+partial sum +RoPE) + MFMA Mt build, merged
  attn_mt<<<dim3(4, 16, 4), 256, 0, stream>>>(kvp, lq, WpT, Mt);

  // out[b] = G[b] @ Mt[b]^T (fp32 out, overwrites kvp scratch) — 16x16 control
  gemm256o<<<dim3(16, 4, 4), 512, 0, stream>>>(G, Mt, out, 1024, 1024,
                                               4096LL * 1024, 1024LL * 1024, 4096LL * 1024);
}

// Round 17
// 136.747 us; speedup vs baseline: 1.0307x; 1.0307x over previous
//
#include <hip/hip_runtime.h>
#include <hip/hip_bf16.h>

// MultiLatentAttention on MI355X.
// causal mask t<=l with L=64 => attention only over first 64 tokens.
// out[b] = softmax_groups(x@Wg) @ M[b],  M built from attn_out and Wp (MFMA).
// Round 17: exact revert to the round-14 consolidated best (133.7us).
// 32x32-MFMA arm falsified (4-way bank conflicts from the fragment read pattern,
// 3.1M conflicts, 58.5us); 8 GEMM schedule variants total bracket the 2-phase
// 256^2 kernel at 48.7us — it stays.

typedef __attribute__((ext_vector_type(8))) short bf16x8;
typedef __attribute__((ext_vector_type(4))) float f32x4;
typedef __attribute__((ext_vector_type(4))) unsigned short us4;

__device__ __forceinline__ void gll16(const void* g, void* l) {
  __builtin_amdgcn_global_load_lds((const __attribute__((address_space(1))) void*)g,
                                   (__attribute__((address_space(3))) void*)l, 16, 0, 0);
}

// ---------------- prep: x->bf16 (blocks 0..2047) + 4 weight transposes (2048..6143) ----------
__global__ __launch_bounds__(256)
void prep_kernel(const float* __restrict__ x, __hip_bfloat16* __restrict__ xb,
                 const float* __restrict__ Wg, const float* __restrict__ Wk,
                 const float* __restrict__ Wv, const float* __restrict__ Wp,
                 __hip_bfloat16* __restrict__ WgT, __hip_bfloat16* __restrict__ WkT,
                 __hip_bfloat16* __restrict__ WvT, __hip_bfloat16* __restrict__ WpT) {
  const int bid = blockIdx.x, tid = threadIdx.x;
  if (bid < 2048) {
    const int stride = 2048 * 256;
    for (int i = bid * 256 + tid; i < 4194304; i += stride) {
      float4 f = reinterpret_cast<const float4*>(x)[i];
      union { __hip_bfloat16 h[4]; us4 v; } u;
      u.h[0] = __float2bfloat16(f.x);
      u.h[1] = __float2bfloat16(f.y);
      u.h[2] = __float2bfloat16(f.z);
      u.h[3] = __float2bfloat16(f.w);
      reinterpret_cast<us4*>(xb)[i] = u.v;
    }
  } else {
    const int t = bid - 2048;
    const int z = t >> 10, rem = t & 1023;
    const float* W = (z == 0) ? Wg : ((z == 1) ? Wk : ((z == 2) ? Wv : Wp));
    __hip_bfloat16* Wt = (z == 0) ? WgT : ((z == 1) ? WkT : ((z == 2) ? WvT : WpT));
    __shared__ float tile[32][33];
    const int bx = (rem & 31) * 32, by = (rem >> 5) * 32;
    const int tx = tid & 31, ty = tid >> 5;  // 32x8
    #pragma unroll
    for (int j = 0; j < 32; j += 8)
      tile[ty + j][tx] = W[(size_t)(by + ty + j) * 1024 + bx + tx];
    __syncthreads();
    #pragma unroll
    for (int j = 0; j < 32; j += 8)
      Wt[(size_t)(bx + ty + j) * 1024 + by + tx] = __float2bfloat16(tile[tx][ty + j]);
  }
}

// ---------------- 256x256 2-phase pipelined bf16 GEMM (proven ~48.7us) ----------------
// 8 waves (2Mx4N), BK=64, double-buffered 128KiB LDS. LDS swizzle: 16B-chunk ^= (row&7),
// pre-swizzled on the GLOBAL source (gll16 dest linear), applied on fragment reads.
// EPI=0: fp32 store. EPI=1: per-64-column-group softmax, bf16 store (gates).
template <int EPI>
__global__ __launch_bounds__(512, 2)
void gemm256(const __hip_bfloat16* __restrict__ A, const __hip_bfloat16* __restrict__ Bt,
             void* __restrict__ Cv, int K, int ldc,
             long long astride, long long bstride, long long cstride) {
  __shared__ __align__(16) unsigned short SA[2][256 * 64];
  __shared__ __align__(16) unsigned short SB[2][256 * 64];
  const int tid = threadIdx.x;
  const int lane = tid & 63;
  const int w = tid >> 6;            // wave 0..7
  const int wm = w >> 2, wn = w & 3; // 2x4 wave grid; per-wave out = 128x64
  const int lr = lane & 15, lk = lane >> 4;
  const int m0 = blockIdx.x * 256, n0 = blockIdx.y * 256;
  const long long b = blockIdx.z;
  const __hip_bfloat16* Ab = A + b * astride;
  const __hip_bfloat16* Bb = Bt + b * bstride;

  f32x4 acc[8][4] = {};

  const int NT = K >> 6;
  int buf = 0;

  auto STAGE = [&](int bsel, int kt) {
    #pragma unroll
    for (int r = 0; r < 4; ++r) {
      int c = r * 512 + tid;          // chunk 0..2047: row=c>>3, slot=c&7
      int row = c >> 3, slot = c & 7;
      int gch = slot ^ (row & 7);     // pre-swizzled global chunk
      gll16(Ab + (size_t)(m0 + row) * K + kt + gch * 8, (char*)&SA[bsel][0] + c * 16);
      gll16(Bb + (size_t)(n0 + row) * K + kt + gch * 8, (char*)&SB[bsel][0] + c * 16);
    }
  };

  STAGE(0, 0);
  __syncthreads();

  for (int t = 0; t < NT; ++t) {
    if (t + 1 < NT) STAGE(buf ^ 1, (t + 1) << 6);

    bf16x8 bfr[2][4];
    #pragma unroll
    for (int kk = 0; kk < 2; ++kk)
      #pragma unroll
      for (int ni = 0; ni < 4; ++ni) {
        int row = wn * 64 + ni * 16 + lr;
        int ch = (kk * 4 + lk) ^ (row & 7);
        bfr[kk][ni] = *(const bf16x8*)&SB[buf][row * 64 + ch * 8];
      }
    #pragma unroll
    for (int mi = 0; mi < 8; ++mi) {
      int row = wm * 128 + mi * 16 + lr;
      int ch0 = lk ^ (row & 7);
      int ch1 = (4 + lk) ^ (row & 7);
      bf16x8 a0 = *(const bf16x8*)&SA[buf][row * 64 + ch0 * 8];
      bf16x8 a1 = *(const bf16x8*)&SA[buf][row * 64 + ch1 * 8];
      #pragma unroll
      for (int ni = 0; ni < 4; ++ni)
        acc[mi][ni] = __builtin_amdgcn_mfma_f32_16x16x32_bf16(a0, bfr[0][ni], acc[mi][ni], 0, 0, 0);
      #pragma unroll
      for (int ni = 0; ni < 4; ++ni)
        acc[mi][ni] = __builtin_amdgcn_mfma_f32_16x16x32_bf16(a1, bfr[1][ni], acc[mi][ni], 0, 0, 0);
    }
    __syncthreads();
    buf ^= 1;
  }

  if (EPI == 0) {
    float* C = (float*)Cv + b * cstride;
    #pragma unroll
    for (int mi = 0; mi < 8; ++mi) {
      int r = m0 + wm * 128 + mi * 16 + lk * 4;
      #pragma unroll
      for (int ni = 0; ni < 4; ++ni) {
        int c = n0 + wn * 64 + ni * 16 + lr;
        #pragma unroll
        for (int jj = 0; jj < 4; ++jj)
          C[(size_t)(r + jj) * ldc + c] = acc[mi][ni][jj];
      }
    }
  } else {
    // Each wave's 64 columns = one softmax group (head h, l=0..63).
    __hip_bfloat16* C = (__hip_bfloat16*)Cv + b * cstride;
    #pragma unroll
    for (int mi = 0; mi < 8; ++mi) {
      #pragma unroll
      for (int jj = 0; jj < 4; ++jj) {
        float mx = -3.0e38f;
        #pragma unroll
        for (int ni = 0; ni < 4; ++ni) mx = fmaxf(mx, acc[mi][ni][jj]);
        mx = fmaxf(mx, __shfl_xor(mx, 1));
        mx = fmaxf(mx, __shfl_xor(mx, 2));
        mx = fmaxf(mx, __shfl_xor(mx, 4));
        mx = fmaxf(mx, __shfl_xor(mx, 8));
        float e[4];
        float s = 0.f;
        #pragma unroll
        for (int ni = 0; ni < 4; ++ni) { e[ni] = __expf(acc[mi][ni][jj] - mx); s += e[ni]; }
        s += __shfl_xor(s, 1);
        s += __shfl_xor(s, 2);
        s += __shfl_xor(s, 4);
        s += __shfl_xor(s, 8);
        float inv = 1.0f / s;
        int r = m0 + wm * 128 + mi * 16 + lk * 4 + jj;
        #pragma unroll
        for (int ni = 0; ni < 4; ++ni)
          C[(size_t)r * ldc + n0 + wn * 64 + ni * 16 + lr] = __float2bfloat16(e[ni] * inv);
      }
    }
  }
}

// ---------------- kv projection, split-K=8: kvp[ks][256][2048] fp32 partials ----------------
// Stacked rows (b*64+t, t<64). 128x128 tile, BK=32, 4 waves, 4 K-iters/block, grid (2,16,8).
__global__ __launch_bounds__(256)
void gemm_kv(const __hip_bfloat16* __restrict__ A, const __hip_bfloat16* __restrict__ Bt,
             float* __restrict__ kvp) {
  __shared__ __align__(16) unsigned short As[128 * 32];
  __shared__ __align__(16) unsigned short Bs[128 * 32];
  const int tid = threadIdx.x;
  const int lane = tid & 63;
  const int w = tid >> 6;
  const int wm = w >> 1, wn = w & 1;
  const int lr = lane & 15, lk = lane >> 4;
  const int m0 = blockIdx.x * 128, n0 = blockIdx.y * 128;
  const int ks = blockIdx.z;
  const int K = 1024;

  f32x4 acc[4][4] = {};
  const int r0 = tid >> 2;
  const int c8 = (tid & 3) * 8;

  auto xrow = [&](int rg) { return (size_t)(rg >> 6) * 4096 + (rg & 63); };

  for (int ki = 0; ki < 4; ++ki) {
    int kt = ks * 128 + ki * 32;
    __syncthreads();
    gll16(A + xrow(m0 + r0) * K + kt + c8,      (char*)As + (w * 64) * 16);
    gll16(Bt + (size_t)(n0 + r0) * K + kt + c8, (char*)Bs + (w * 64) * 16);
    gll16(A + xrow(m0 + 64 + r0) * K + kt + c8,      (char*)As + (256 + w * 64) * 16);
    gll16(Bt + (size_t)(n0 + 64 + r0) * K + kt + c8, (char*)Bs + (256 + w * 64) * 16);
    __syncthreads();

    bf16x8 af[4], bf[4];
    #pragma unroll
    for (int mi = 0; mi < 4; ++mi)
      af[mi] = *(const bf16x8*)&As[(wm * 64 + mi * 16 + lr) * 32 + lk * 8];
    #pragma unroll
    for (int ni = 0; ni < 4; ++ni)
      bf[ni] = *(const bf16x8*)&Bs[(wn * 64 + ni * 16 + lr) * 32 + lk * 8];
    #pragma unroll
    for (int mi = 0; mi < 4; ++mi)
      #pragma unroll
      for (int ni = 0; ni < 4; ++ni)
        acc[mi][ni] = __builtin_amdgcn_mfma_f32_16x16x32_bf16(af[mi], bf[ni], acc[mi][ni], 0, 0, 0);
  }

  float* C = kvp + (size_t)ks * 256 * 2048;
  #pragma unroll
  for (int mi = 0; mi < 4; ++mi) {
    int r = m0 + wm * 64 + mi * 16 + lk * 4;
    #pragma unroll
    for (int ni = 0; ni < 4; ++ni) {
      int c = n0 + wn * 64 + ni * 16 + lr;
      #pragma unroll
      for (int jj = 0; jj < 4; ++jj)
        C[(size_t)(r + jj) * 2048 + c] = acc[mi][ni][jj];
    }
  }
}

// ---------------- attn (split-K sum + RoPE) + MFMA Mt build, merged: grid (4ct,16h,4b) -------
// WpT slice staged via gll16 FIRST (lands under attention compute). ao written to LDS bf16
// with ^(row&7) swizzle (plain ds_write). Mt_slice[256c][64l] = SW @ SAo^T via MFMA.
__global__ __launch_bounds__(256)
void attn_mt(const float* __restrict__ kvp, const float* __restrict__ lq,
             const __hip_bfloat16* __restrict__ WpT, __hip_bfloat16* __restrict__ Mt) {
  const int ct = blockIdx.x, h = blockIdx.y, b = blockIdx.z;
  __shared__ float Ks[64][64];
  __shared__ float Vs[64][64];
  __shared__ float S[64][65];   // S[l][t]
  __shared__ float Pt[64][65];  // Pt[t][l]
  __shared__ __align__(16) unsigned short SW[256 * 64];   // WpT slice [256c][64d], swizzled
  __shared__ __align__(16) unsigned short SAo[64 * 64];   // ao bf16 [64l][64d], swizzled
  const int tid = threadIdx.x;
  const int lane = tid & 63;
  const int w = tid >> 6;
  const int lr = lane & 15, lk = lane >> 4;

  // stage WpT slice early — overlaps the whole attention phase
  #pragma unroll
  for (int j = 0; j < 8; ++j) {
    int c2 = j * 256 + tid;
    int row = c2 >> 3, slot = c2 & 7;
    int gch = slot ^ (row & 7);
    gll16(WpT + (size_t)(ct * 256 + row) * 1024 + h * 64 + gch * 8, (char*)SW + c2 * 16);
  }

  // ---- K/V: sum 8 split-K partials + RoPE on K ----
  {
    int r = tid >> 4;            // 0..15
    int c4 = (tid & 15) * 4;     // head-dim col (pairs i0=c4/2, i0+1)
    int i0 = c4 >> 1;
    float inv0 = exp2f(-13.287712379549449f * ((float)i0 * (1.0f / 32.0f)));
    float inv1 = exp2f(-13.287712379549449f * ((float)(i0 + 1) * (1.0f / 32.0f)));
    #pragma unroll
    for (int j = 0; j < 4; ++j) {
      int row = j * 16 + r;      // t
      float4 kf = make_float4(0.f, 0.f, 0.f, 0.f);
      float4 vf = make_float4(0.f, 0.f, 0.f, 0.f);
      #pragma unroll
      for (int ks = 0; ks < 8; ++ks) {
        const float* base = kvp + ((size_t)ks * 256 + b * 64 + row) * 2048 + h * 64;
        float4 kp = *(const float4*)(base + c4);
        float4 vp = *(const float4*)(base + 1024 + c4);
        kf.x += kp.x; kf.y += kp.y; kf.z += kp.z; kf.w += kp.w;
        vf.x += vp.x; vf.y += vp.y; vf.z += vp.z; vf.w += vp.w;
      }
      float a0 = (float)row * inv0, a1 = (float)row * inv1;
      float s0 = sinf(a0), c0 = cosf(a0), s1 = sinf(a1), c1 = cosf(a1);
      *(float4*)&Ks[row][c4] = make_float4(kf.x * c0 - kf.y * s0, kf.x * s0 + kf.y * c0,
                                           kf.z * c1 - kf.w * s1, kf.z * s1 + kf.w * c1);
      *(float4*)&Vs[row][c4] = vf;
    }
  }
  __syncthreads();

  // ---- scores: thread = (l = lane, t-chunk = wave) ----
  {
    const int l = tid & 63;
    float q[64];
    const float4* lq4 = (const float4*)(lq + ((size_t)l * 16 + h) * 64);
    #pragma unroll
    for (int i = 0; i < 16; ++i) {
      float4 f = lq4[i];
      q[4 * i] = f.x; q[4 * i + 1] = f.y; q[4 * i + 2] = f.z; q[4 * i + 3] = f.w;
    }
    #pragma unroll
    for (int tl = 0; tl < 16; ++tl) {
      int t = w * 16 + tl;
      float a = 0.f;
      #pragma unroll
      for (int d4 = 0; d4 < 16; ++d4) {
        float4 kf = *(const float4*)&Ks[t][d4 * 4];
        a += q[4 * d4] * kf.x + q[4 * d4 + 1] * kf.y + q[4 * d4 + 2] * kf.z + q[4 * d4 + 3] * kf.w;
      }
      S[l][t] = a * 0.125f;
    }
  }
  __syncthreads();

  // ---- softmax: thread = (l = tid>>2, c = tid&3), causal t<=l ----
  {
    const int l = tid >> 2, c = tid & 3;
    float sv[16];
    float mx = -3.0e38f;
    #pragma unroll
    for (int i = 0; i < 16; ++i) {
      int t = c * 16 + i;
      sv[i] = S[l][t];
      if (t <= l) mx = fmaxf(mx, sv[i]);
    }
    mx = fmaxf(mx, __shfl_xor(mx, 1));
    mx = fmaxf(mx, __shfl_xor(mx, 2));
    float sum = 0.f;
    float e[16];
    #pragma unroll
    for (int i = 0; i < 16; ++i) {
      int t = c * 16 + i;
      e[i] = (t <= l) ? __expf(sv[i] - mx) : 0.f;
      sum += e[i];
    }
    sum += __shfl_xor(sum, 1);
    sum += __shfl_xor(sum, 2);
    float inv = 1.0f / sum;
    #pragma unroll
    for (int i = 0; i < 16; ++i) Pt[c * 16 + i][l] = e[i] * inv;
  }
  __syncthreads();

  // ---- PV: thread = (l = lane, d-chunk = wave); ao -> SAo bf16 swizzled ----
  {
    const int l = tid & 63;
    float o[16];
    #pragma unroll
    for (int i = 0; i < 16; ++i) o[i] = 0.f;
    for (int t = 0; t < 64; ++t) {
      float p = Pt[t][l];
      #pragma unroll
      for (int d4 = 0; d4 < 4; ++d4) {
        float4 vf = *(const float4*)&Vs[t][w * 16 + d4 * 4];
        o[4 * d4]     += p * vf.x;
        o[4 * d4 + 1] += p * vf.y;
        o[4 * d4 + 2] += p * vf.z;
        o[4 * d4 + 3] += p * vf.w;
      }
    }
    union { __hip_bfloat16 hh[8]; bf16x8 v; } p0, p1;
    #pragma unroll
    for (int i = 0; i < 8; ++i) { p0.hh[i] = __float2bfloat16(o[i]); p1.hh[i] = __float2bfloat16(o[8 + i]); }
    // logical d-chunks 2w, 2w+1 of row l at physical chunk ^ (l&7)
    *(bf16x8*)&SAo[l * 64 + ((2 * w) ^ (l & 7)) * 8]     = p0.v;
    *(bf16x8*)&SAo[l * 64 + ((2 * w + 1) ^ (l & 7)) * 8] = p1.v;
  }
  __syncthreads();  // drains SAo ds_writes AND SW gll16 (vmcnt)

  // ---- MFMA: Mt_slice = SW @ SAo^T ----
  f32x4 acc[4][4] = {};
  bf16x8 bfr[2][4];
  #pragma unroll
  for (int kk = 0; kk < 2; ++kk)
    #pragma unroll
    for (int ni = 0; ni < 4; ++ni) {
      int row = ni * 16 + lr;
      int ch = (kk * 4 + lk) ^ (row & 7);
      bfr[kk][ni] = *(const bf16x8*)&SAo[row * 64 + ch * 8];
    }
  #pragma unroll
  for (int mi = 0; mi < 4; ++mi) {
    int row = w * 64 + mi * 16 + lr;
    int ch0 = lk ^ (row & 7);
    int ch1 = (4 + lk) ^ (row & 7);
    bf16x8 a0 = *(const bf16x8*)&SW[row * 64 + ch0 * 8];
    bf16x8 a1 = *(const bf16x8*)&SW[row * 64 + ch1 * 8];
    #pragma unroll
    for (int ni = 0; ni < 4; ++ni)
      acc[mi][ni] = __builtin_amdgcn_mfma_f32_16x16x32_bf16(a0, bfr[0][ni], acc[mi][ni], 0, 0, 0);
    #pragma unroll
    for (int ni = 0; ni < 4; ++ni)
      acc[mi][ni] = __builtin_amdgcn_mfma_f32_16x16x32_bf16(a1, bfr[1][ni], acc[mi][ni], 0, 0, 0);
  }

  // C-layout: row(c) = ct*256 + w*64 + mi*16 + lk*4 + jj, col(l) = ni*16 + lr
  #pragma unroll
  for (int mi = 0; mi < 4; ++mi) {
    int c = ct * 256 + w * 64 + mi * 16 + lk * 4;
    #pragma unroll
    for (int ni = 0; ni < 4; ++ni) {
      int l = ni * 16 + lr;
      #pragma unroll
      for (int jj = 0; jj < 4; ++jj)
        Mt[((size_t)b * 1024 + c + jj) * 1024 + h * 64 + l] = __float2bfloat16(acc[mi][ni][jj]);
    }
  }
}

extern "C" void kernel_launch(void* const* d_in, const int* in_sizes, int n_in,
                              void* d_out, int out_size, void* d_ws, size_t ws_size,
                              hipStream_t stream) {
  const float* x  = (const float*)d_in[0];
  const float* lq = (const float*)d_in[1];
  const float* Wk = (const float*)d_in[2];
  const float* Wv = (const float*)d_in[3];
  const float* Wg = (const float*)d_in[4];
  const float* Wp = (const float*)d_in[5];
  float* out = (float*)d_out;

  // workspace layout (bytes)
  char* w = (char*)d_ws;
  __hip_bfloat16* xb   = (__hip_bfloat16*)(w);              // 33,554,432
  __hip_bfloat16* G    = (__hip_bfloat16*)(w + 33554432);   // 33,554,432
  __hip_bfloat16* WgT  = (__hip_bfloat16*)(w + 67108864);   // 2,097,152
  __hip_bfloat16* WkvT = (__hip_bfloat16*)(w + 69206016);   // 4,194,304
  __hip_bfloat16* WpT  = (__hip_bfloat16*)(w + 73400320);   // 2,097,152
  __hip_bfloat16* Mt   = (__hip_bfloat16*)(w + 75497472);   // 8,388,608
  // total 83,886,080 B
  // kv partials live in d_out (16MB of its 64MB), consumed by attn_mt before
  // the final GEMM overwrites all of d_out. Deterministic.
  float* kvp = out;

  // x->bf16 + 4 weight transposes, one launch
  prep_kernel<<<6144, 256, 0, stream>>>(x, xb, Wg, Wk, Wv, Wp,
                                        WgT, WkvT, WkvT + 1024 * 1024, WpT);

  // gates: G = softmax_groups(x @ Wg), bf16 [16384,1024] (proven 2-phase)
  gemm256<1><<<dim3(64, 4, 1), 512, 0, stream>>>(xb, WgT, G, 1024, 1024, 0LL, 0LL, 0LL);

  // k,v split-K partials: kvp[8][256][2048] fp32 (stacked rows b*64+t)
  gemm_kv<<<dim3(2, 16, 8), 256, 0, stream>>>(xb, WkvT, kvp);

  // attention (+partial sum +RoPE) + MFMA Mt build, merged
  attn_mt<<<dim3(4, 16, 4), 256, 0, stream>>>(kvp, lq, WpT, Mt);

  // out[b] = G[b] @ Mt[b]^T (fp32 out, overwrites kvp scratch) (proven 2-phase)
  gemm256<0><<<dim3(16, 4, 4), 512, 0, stream>>>(G, Mt, out, 1024, 1024,
                                                 4096LL * 1024, 1024LL * 1024, 4096LL * 1024);
}